// Round 18
// baseline (538.903 us; speedup 1.0000x reference)
//
#include <hip/hip_runtime.h>

#define N_NODES 50000
#define E_EDGES 1600000
#define E2 (E_EDGES + N_NODES)   // 1,650,000 with self loops
#define HEADS 4
#define F 256
#define OUTC 10
#define BN_EPS 1e-5f
#define NEG_SLOPE 0.2f
#define NSLICE 64                // stats atomic-spreading slices
#define SB 1024                  // scan block size
#define NB ((N_NODES + SB - 1) / SB)   // 49 scan blocks

// XCD-ranged edge processing (scatter + count): 8 dst-ranges
#define NXCD 8
#define NR (N_NODES / NXCD)                  // 6250 nodes per range
#define EPB 2048                             // edges per block-chunk
#define NCHUNK ((E2 + EPB - 1) / EPB)        // 806 chunks

// mega_prep block ranges
#define CXB (N_NODES * 128 / 4 / 256)        // 6250 convert_x blocks
#define CWB 128                               // convert_w1T blocks
#define CDB (NXCD * NCHUNK)                   // 6448 ranged count_deg blocks

#define GEMM_BLOCKS ((N_NODES + 63) / 64)    // 782

static_assert(N_NODES % 4 == 0, "grid_nw exact");
static_assert(N_NODES % NXCD == 0, "ranges exact");

typedef __attribute__((ext_vector_type(8))) short short8;
typedef __attribute__((ext_vector_type(4))) float f32x4;
typedef _Float16 f16;
typedef __attribute__((ext_vector_type(2))) _Float16 f16x2;

__device__ __forceinline__ unsigned short f2h(float f) {
    f16 h = (f16)f;
    return __builtin_bit_cast(unsigned short, h);
}
__device__ __forceinline__ float h2f(unsigned short b) {
    return (float)__builtin_bit_cast(f16, b);
}
__device__ __forceinline__ f16x2 u2h2(unsigned int u) {
    return __builtin_bit_cast(f16x2, u);
}
__device__ __forceinline__ unsigned int h22u(f16x2 h) {
    return __builtin_bit_cast(unsigned int, h);
}

// ---- fused prep: convert_x | convert_w1T | ranged count_deg ----
__global__ __launch_bounds__(256) void mega_prep(
    const float* __restrict__ X, unsigned short* __restrict__ Xh,
    const float* __restrict__ W1, unsigned short* __restrict__ WT,
    const int* __restrict__ eidx, int* __restrict__ deg)
{
    const int b = blockIdx.x;
    const int t = threadIdx.x;
    if (b < CXB) {
        const int i = b * 256 + t;                 // float4 index, exact
        float4 v = reinterpret_cast<const float4*>(X)[i];
        ushort4 o = { f2h(v.x), f2h(v.y), f2h(v.z), f2h(v.w) };
        reinterpret_cast<ushort4*>(Xh)[i] = o;
    } else if (b < CXB + CWB) {
        const int k = b - CXB;                     // W1 row
        WT[t * 128 + k] = f2h(W1[k * 256 + t]);
    } else {
        const int b2 = b - CXB - CWB;
        const int r = b2 & (NXCD - 1);
        const int chunk = b2 >> 3;
        const int lo = r * NR;
        const int base = chunk * EPB;
        for (int i = t; i < EPB; i += 256) {
            const int e = base + i;
            if (e >= E2) break;
            int dst = (e < E_EDGES) ? eidx[E_EDGES + e] : e - E_EDGES;
            if ((unsigned)(dst - lo) >= (unsigned)NR) continue;
            atomicAdd(&deg[dst], 1);
        }
    }
}

// ---- parallel scan, 2 dispatches (R15-proven) ----
__global__ __launch_bounds__(SB) void scan_blocks(
    const int* __restrict__ deg, int* __restrict__ rowptr, int* __restrict__ bsum)
{
    __shared__ int sm[SB];
    const int t = threadIdx.x;
    const int idx = blockIdx.x * SB + t;
    int v = (idx < N_NODES) ? deg[idx] : 0;
    sm[t] = v;
    __syncthreads();
    for (int off = 1; off < SB; off <<= 1) {
        int u = (t >= off) ? sm[t - off] : 0;
        __syncthreads();
        sm[t] += u;
        __syncthreads();
    }
    if (idx < N_NODES) rowptr[idx] = sm[t] - v;   // exclusive within block
    if (t == SB - 1) bsum[blockIdx.x] = sm[t];
}

__global__ __launch_bounds__(SB) void scan_add2(
    int* __restrict__ rowptr, const int* __restrict__ bsum)
{
    __shared__ int boff_s;
    if (threadIdx.x == 0) {
        int run = 0;
        for (int b = 0; b < (int)blockIdx.x; b++) run += bsum[b];
        boff_s = run;
        if (blockIdx.x == 0) {
            int tot = 0;
            for (int b = 0; b < NB; b++) tot += bsum[b];
            rowptr[N_NODES] = tot;
        }
    }
    __syncthreads();
    const int idx = blockIdx.x * SB + threadIdx.x;
    if (idx < N_NODES) rowptr[idx] += boff_s;
}

// ---- ranged scatter (R15-proven, STANDALONE — co-residency with gemm
// evicts the esrc/cursor L2 slices and reintroduces RMW amplification) --
__global__ __launch_bounds__(256) void scatter_edges8(
    const int* __restrict__ eidx, const int* __restrict__ rowptr,
    int* __restrict__ cursor, int* __restrict__ esrc)
{
    const int r = blockIdx.x & (NXCD - 1);
    const int chunk = blockIdx.x >> 3;
    const int lo = r * NR;
    const int base = chunk * EPB;
    for (int i = threadIdx.x; i < EPB; i += 256) {
        const int e = base + i;
        if (e >= E2) break;
        int dst = (e < E_EDGES) ? eidx[E_EDGES + e] : e - E_EDGES;
        if ((unsigned)(dst - lo) >= (unsigned)NR) continue;
        int src = (e < E_EDGES) ? eidx[e] : dst;
        int pos = atomicAdd(&cursor[dst], 1);
        esrc[rowptr[dst] + pos] = src;
    }
}

// ------- MFMA GEMM (fp16) + fused S/D ---------------------------------
template<int K, bool BROW>
__global__ __launch_bounds__(256) void gemm_sd(
    const unsigned short* __restrict__ A, const unsigned short* __restrict__ BT,
    const float* __restrict__ brow, const float* __restrict__ a_src,
    const float* __restrict__ a_dst, unsigned short* __restrict__ C,
    float* __restrict__ S, float* __restrict__ D)
{
    const int t = threadIdx.x;
    const int wave = t >> 6, lane = t & 63;
    const int lo = lane & 15, hi = lane >> 4;
    const int row0 = blockIdx.x * 64;
    const int nbase = wave * 64;

    int arow[4];
#pragma unroll
    for (int m = 0; m < 4; m++)
        arow[m] = min(row0 + m * 16 + lo, N_NODES - 1);

    f32x4 acc[4][4];
#pragma unroll
    for (int m = 0; m < 4; m++)
#pragma unroll
        for (int n = 0; n < 4; n++)
            acc[m][n] = (f32x4){0.f, 0.f, 0.f, 0.f};

    for (int k0 = 0; k0 < K; k0 += 32) {
        const int kk = k0 + hi * 8;
        short8 af[4], bfr[4];
#pragma unroll
        for (int m = 0; m < 4; m++)
            af[m] = *reinterpret_cast<const short8*>(A + (size_t)arow[m] * K + kk);
#pragma unroll
        for (int n = 0; n < 4; n++)
            bfr[n] = *reinterpret_cast<const short8*>(BT + (size_t)(nbase + n * 16 + lo) * K + kk);
#pragma unroll
        for (int m = 0; m < 4; m++)
#pragma unroll
            for (int n = 0; n < 4; n++)
                acc[m][n] = __builtin_amdgcn_mfma_f32_16x16x32_f16(
                    af[m], bfr[n], acc[m][n], 0, 0, 0);
    }

    float bb[4], asv[4], adv[4];
#pragma unroll
    for (int n = 0; n < 4; n++) {
        int col = nbase + n * 16 + lo;
        bb[n]  = BROW ? brow[col] : 0.f;
        asv[n] = a_src[col];
        adv[n] = a_dst[col];
    }

#pragma unroll
    for (int m = 0; m < 4; m++) {
#pragma unroll
        for (int i = 0; i < 4; i++) {
            const int row = row0 + m * 16 + hi * 4 + i;
            const bool ok = row < N_NODES;
            float ps = 0.f, pd = 0.f;
#pragma unroll
            for (int n = 0; n < 4; n++) {
                float v = acc[m][n][i] + bb[n];
                ps += v * asv[n];
                pd += v * adv[n];
                if (ok) C[(size_t)row * F + nbase + n * 16 + lo] = f2h(v);
            }
#pragma unroll
            for (int off = 1; off < 16; off <<= 1) {
                ps += __shfl_xor(ps, off, 64);
                pd += __shfl_xor(pd, off, 64);
            }
            if (lo == 0 && ok) {
                S[row * HEADS + wave] = ps;
                D[row * HEADS + wave] = pd;
            }
        }
    }
}

// ------- fused softmax + aggregation + bias + ReLU + sliced stats ------
// R16-proven fp16 inner loop (118 us, VGPR 32, occ 80%).
__global__ __launch_bounds__(256) void gat_aggregate(
    const int* __restrict__ rowptr, const int* __restrict__ esrc,
    const float* __restrict__ S, const float* __restrict__ D,
    const unsigned short* __restrict__ XWh, const float* __restrict__ bias,
    unsigned short* __restrict__ Hh, float* __restrict__ stp)
{
    __shared__ int          sbuf[4][64];
    __shared__ unsigned int wbuf[4][64][4];   // half2-packed w per head
    __shared__ float red_s[4][F];
    __shared__ float red_q[4][F];
    const int wv   = threadIdx.x >> 6;
    const int lane = threadIdx.x & 63;
    const int dst  = blockIdx.x * 4 + wv;
    const int beg = rowptr[dst], end = rowptr[dst + 1];
    const int h = lane >> 4;
    const float4 d4 = *reinterpret_cast<const float4*>(D + dst * HEADS);

    f16x2 a01a = {0, 0}, a23a = {0, 0}, dna = {0, 0};
    f16x2 a01b = {0, 0}, a23b = {0, 0}, dnb = {0, 0};

    for (int i = beg; i < end; i += 64) {
        const int nb = min(64, end - i);
        const bool valid = (i + lane < end);
        const int mysrc = valid ? esrc[i + lane] : 0;
        float4 w4 = {0.f, 0.f, 0.f, 0.f};
        if (valid) {
            const float4 s4 = *reinterpret_cast<const float4*>(S + mysrc * HEADS);
            float z;
            z = s4.x + d4.x; w4.x = __expf(z > 0.f ? z : NEG_SLOPE * z);
            z = s4.y + d4.y; w4.y = __expf(z > 0.f ? z : NEG_SLOPE * z);
            z = s4.z + d4.z; w4.z = __expf(z > 0.f ? z : NEG_SLOPE * z);
            z = s4.w + d4.w; w4.w = __expf(z > 0.f ? z : NEG_SLOPE * z);
        }
        sbuf[wv][lane] = mysrc;
        {
            f16 hx = (f16)w4.x, hy = (f16)w4.y, hz = (f16)w4.z, hw = (f16)w4.w;
            wbuf[wv][lane][0] = h22u((f16x2){hx, hx});
            wbuf[wv][lane][1] = h22u((f16x2){hy, hy});
            wbuf[wv][lane][2] = h22u((f16x2){hz, hz});
            wbuf[wv][lane][3] = h22u((f16x2){hw, hw});
        }

        int j = 0;
        for (; j + 7 < nb; j += 8) {
            int s0 = sbuf[wv][j + 0], s1 = sbuf[wv][j + 1];
            int s2 = sbuf[wv][j + 2], s3 = sbuf[wv][j + 3];
            int s4i = sbuf[wv][j + 4], s5 = sbuf[wv][j + 5];
            int s6 = sbuf[wv][j + 6], s7 = sbuf[wv][j + 7];
            f16x2 w0 = u2h2(wbuf[wv][j + 0][h]), w1 = u2h2(wbuf[wv][j + 1][h]);
            f16x2 w2 = u2h2(wbuf[wv][j + 2][h]), w3 = u2h2(wbuf[wv][j + 3][h]);
            f16x2 w4f = u2h2(wbuf[wv][j + 4][h]), w5 = u2h2(wbuf[wv][j + 5][h]);
            f16x2 w6 = u2h2(wbuf[wv][j + 6][h]), w7 = u2h2(wbuf[wv][j + 7][h]);
            uint2 x0 = *reinterpret_cast<const uint2*>(XWh + (size_t)s0 * F + lane * 4);
            uint2 x1 = *reinterpret_cast<const uint2*>(XWh + (size_t)s1 * F + lane * 4);
            uint2 x2 = *reinterpret_cast<const uint2*>(XWh + (size_t)s2 * F + lane * 4);
            uint2 x3 = *reinterpret_cast<const uint2*>(XWh + (size_t)s3 * F + lane * 4);
            uint2 x4 = *reinterpret_cast<const uint2*>(XWh + (size_t)s4i * F + lane * 4);
            uint2 x5 = *reinterpret_cast<const uint2*>(XWh + (size_t)s5 * F + lane * 4);
            uint2 x6 = *reinterpret_cast<const uint2*>(XWh + (size_t)s6 * F + lane * 4);
            uint2 x7 = *reinterpret_cast<const uint2*>(XWh + (size_t)s7 * F + lane * 4);
            a01a += w0 * u2h2(x0.x); a23a += w0 * u2h2(x0.y); dna += w0;
            a01b += w1 * u2h2(x1.x); a23b += w1 * u2h2(x1.y); dnb += w1;
            a01a += w2 * u2h2(x2.x); a23a += w2 * u2h2(x2.y); dna += w2;
            a01b += w3 * u2h2(x3.x); a23b += w3 * u2h2(x3.y); dnb += w3;
            a01a += w4f * u2h2(x4.x); a23a += w4f * u2h2(x4.y); dna += w4f;
            a01b += w5 * u2h2(x5.x); a23b += w5 * u2h2(x5.y); dnb += w5;
            a01a += w6 * u2h2(x6.x); a23a += w6 * u2h2(x6.y); dna += w6;
            a01b += w7 * u2h2(x7.x); a23b += w7 * u2h2(x7.y); dnb += w7;
        }
        for (; j < nb; j++) {
            int src = sbuf[wv][j];
            f16x2 wj = u2h2(wbuf[wv][j][h]);
            uint2 xv = *reinterpret_cast<const uint2*>(XWh + (size_t)src * F + lane * 4);
            a01a += wj * u2h2(xv.x); a23a += wj * u2h2(xv.y); dna += wj;
        }
    }

    const float ax = (float)a01a.x + (float)a01b.x;
    const float ay = (float)a01a.y + (float)a01b.y;
    const float az = (float)a23a.x + (float)a23b.x;
    const float aw = (float)a23a.y + (float)a23b.y;
    const float den = (float)dna.x + (float)dnb.x;
    const float inv = 1.f / (den + 1e-16f);
    float4 bv = *reinterpret_cast<const float4*>(bias + lane * 4);
    float v0 = ax * inv + bv.x, v1 = ay * inv + bv.y;
    float v2 = az * inv + bv.z, v3 = aw * inv + bv.w;
    v0 = v0 > 0.f ? v0 : 0.f; v1 = v1 > 0.f ? v1 : 0.f;
    v2 = v2 > 0.f ? v2 : 0.f; v3 = v3 > 0.f ? v3 : 0.f;
    ushort4 o = { f2h(v0), f2h(v1), f2h(v2), f2h(v3) };
    *reinterpret_cast<ushort4*>(Hh + (size_t)dst * F + lane * 4) = o;

    f32x4 rs = {v0, v1, v2, v3};
    f32x4 rq = {v0 * v0, v1 * v1, v2 * v2, v3 * v3};
    *reinterpret_cast<f32x4*>(&red_s[wv][lane * 4]) = rs;
    *reinterpret_cast<f32x4*>(&red_q[wv][lane * 4]) = rq;
    __syncthreads();
    const int ch = threadIdx.x;
    float s = (red_s[0][ch] + red_s[1][ch]) + (red_s[2][ch] + red_s[3][ch]);
    float q = (red_q[0][ch] + red_q[1][ch]) + (red_q[2][ch] + red_q[3][ch]);
    float* slice = stp + (size_t)(blockIdx.x & (NSLICE - 1)) * (2 * F);
    atomicAdd(&slice[ch], s);
    atomicAdd(&slice[F + ch], q);
}

// ---- fold BN1 into W2 + brow, ONE kernel, 33 blocks (R14-proven) ----
__global__ __launch_bounds__(256) void fold1(
    const float* __restrict__ stp, const float* __restrict__ g,
    const float* __restrict__ be, const float* __restrict__ W2,
    unsigned short* __restrict__ WT2h, float* __restrict__ brow)
{
    __shared__ float sc_l[F], sh_l[F];
    const int t = threadIdx.x;
    float s = 0.f, q = 0.f;
    for (int b = 0; b < NSLICE; b++) {       // fixed order
        s += stp[(size_t)b * 2 * F + t];
        q += stp[(size_t)b * 2 * F + F + t];
    }
    const float inv_n = 1.f / (float)N_NODES;
    float mu = s * inv_n;
    float var = q * inv_n - mu * mu;
    float sc = rsqrtf(var + BN_EPS) * g[t];
    sc_l[t] = sc;
    sh_l[t] = be[t] - mu * sc;
    __syncthreads();
    if (blockIdx.x < 32) {
        const int k0 = blockIdx.x * 8;
#pragma unroll
        for (int kk = 0; kk < 8; kk++)
            WT2h[(size_t)t * F + k0 + kk] = f2h(W2[(size_t)(k0 + kk) * F + t] * sc_l[k0 + kk]);
    } else {
        float acc = 0.f;
        for (int k = 0; k < F; k++)
            acc += sh_l[k] * W2[(size_t)k * F + t];
        brow[t] = acc;
    }
}

// ---- BN2 prep + fold into classifier weights, 1 block (R14-proven) ----
__global__ __launch_bounds__(256) void fold_wc(
    const float* __restrict__ stp, const float* __restrict__ g,
    const float* __restrict__ be, const float* __restrict__ Wc,
    const float* __restrict__ bc, float* __restrict__ Wcp, float* __restrict__ bcp)
{
    __shared__ float sc_l[F], sh_l[F];
    __shared__ float red[256][OUTC];
    const int t = threadIdx.x;
    float s = 0.f, q = 0.f;
    for (int b = 0; b < NSLICE; b++) {       // fixed order
        s += stp[(size_t)b * 2 * F + t];
        q += stp[(size_t)b * 2 * F + F + t];
    }
    const float inv_n = 1.f / (float)N_NODES;
    float mu = s * inv_n;
    float var = q * inv_n - mu * mu;
    float sc = rsqrtf(var + BN_EPS) * g[t];
    sc_l[t] = sc;
    sh_l[t] = be[t] - mu * sc;
    const float sh_t = be[t] - mu * sc;
#pragma unroll
    for (int o = 0; o < OUTC; o++) {
        float wv = Wc[t * OUTC + o];
        Wcp[t * OUTC + o] = wv * sc;
        red[t][o] = sh_t * wv;
    }
    __syncthreads();
    for (int off = 128; off > 0; off >>= 1) {
        if (t < off) {
#pragma unroll
            for (int o = 0; o < OUTC; o++)
                red[t][o] += red[t + off][o];
        }
        __syncthreads();
    }
    if (t < OUTC) bcp[t] = bc[t] + red[0][t];
}

// ---------------- classifier: [N,256]fp16 @ Wcp[256,10] + bcp --------
__global__ __launch_bounds__(256) void classifier(
    const unsigned short* __restrict__ Hh, const float* __restrict__ Wcp,
    const float* __restrict__ bcp, float* __restrict__ out)
{
    __shared__ float wls[F][OUTC + 1];
    const int t = threadIdx.x;
    for (int i = t; i < F * OUTC; i += 256)
        wls[i / OUTC][i % OUTC] = Wcp[i];
    __syncthreads();

    const int wave = t >> 6, lane = t & 63;
    const int n = blockIdx.x * 4 + wave;
    if (n >= N_NODES) return;

    float v[4];
#pragma unroll
    for (int j = 0; j < 4; j++)
        v[j] = h2f(Hh[(size_t)n * F + j * 64 + lane]);

    float acc[OUTC];
#pragma unroll
    for (int o = 0; o < OUTC; o++) acc[o] = 0.f;
#pragma unroll
    for (int j = 0; j < 4; j++)
#pragma unroll
        for (int o = 0; o < OUTC; o++)
            acc[o] += v[j] * wls[j * 64 + lane][o];

#pragma unroll
    for (int off = 32; off > 0; off >>= 1)
#pragma unroll
        for (int o = 0; o < OUTC; o++)
            acc[o] += __shfl_xor(acc[o], off, 64);

    if (lane == 0) {
#pragma unroll
        for (int o = 0; o < OUTC; o++)
            out[(size_t)n * OUTC + o] = acc[o] + bcp[o];
    }
}

extern "C" void kernel_launch(void* const* d_in, const int* in_sizes, int n_in,
                              void* d_out, int out_size, void* d_ws, size_t ws_size,
                              hipStream_t stream)
{
    const float* x   = (const float*)d_in[0];
    const int*   ei  = (const int*)d_in[1];
    const float* W1  = (const float*)d_in[2];
    const float* as1 = (const float*)d_in[3];
    const float* ad1 = (const float*)d_in[4];
    const float* b1  = (const float*)d_in[5];
    const float* W2  = (const float*)d_in[6];
    const float* as2 = (const float*)d_in[7];
    const float* ad2 = (const float*)d_in[8];
    const float* b2  = (const float*)d_in[9];
    const float* g1  = (const float*)d_in[10];
    const float* be1 = (const float*)d_in[11];
    const float* g2  = (const float*)d_in[12];
    const float* be2 = (const float*)d_in[13];
    const float* Wc  = (const float*)d_in[14];
    const float* bc  = (const float*)d_in[15];
    float* out = (float*)d_out;

    char* w = (char*)d_ws;
    // zero-init region first (one memset): deg | cursor | stp1 | stp2
    int*   deg   = (int*)w;                      w += (size_t)N_NODES * 4;
    int*   cursor= (int*)w;                      w += (size_t)N_NODES * 4;
    float* stp1  = (float*)w;                    w += (size_t)NSLICE * 2 * F * 4;
    float* stp2  = (float*)w;                    w += (size_t)NSLICE * 2 * F * 4;
    const size_t zero_bytes = (size_t)N_NODES * 8 + (size_t)NSLICE * 2 * F * 8;

    unsigned short* Xh   = (unsigned short*)w;   w += (size_t)N_NODES * 128 * 2;
    unsigned short* XWh  = (unsigned short*)w;   w += (size_t)N_NODES * F * 2;
    unsigned short* Hh   = (unsigned short*)w;   w += (size_t)N_NODES * F * 2;
    unsigned short* WT1h = (unsigned short*)w;   w += 256 * 128 * 2;
    unsigned short* WT2h = (unsigned short*)w;   w += 256 * 256 * 2;
    float* Wcp   = (float*)w;                    w += F * OUTC * 4;
    float* bcp   = (float*)w;                    w += 64;
    float* brow2 = (float*)w;                    w += F * 4;
    float* Sv    = (float*)w;                    w += (size_t)N_NODES * HEADS * 4;
    float* Dv    = (float*)w;                    w += (size_t)N_NODES * HEADS * 4;
    int* rowp    = (int*)w;                      w += (size_t)(N_NODES + 1) * 4;
    int* bsum    = (int*)w;                      w += NB * 4;
    int* esrc    = (int*)w;                      /* E2 ints */

    const int grid_nw   = N_NODES / 4;           // 12500
    const int grid_prep = CXB + CWB + CDB;       // 12826
    const int grid_sc   = NXCD * NCHUNK;         // 6448

    // ---- prep ----
    hipMemsetAsync(deg, 0, zero_bytes, stream);
    mega_prep<<<grid_prep, 256, 0, stream>>>(x, Xh, W1, WT1h, ei, deg);
    scan_blocks<<<NB, SB, 0, stream>>>(deg, rowp, bsum);
    scan_add2<<<NB, SB, 0, stream>>>(rowp, bsum);
    scatter_edges8<<<grid_sc, 256, 0, stream>>>(ei, rowp, cursor, esrc);

    // ---- layer 1 ----
    gemm_sd<128, false><<<GEMM_BLOCKS, 256, 0, stream>>>(
        Xh, WT1h, nullptr, as1, ad1, XWh, Sv, Dv);
    gat_aggregate<<<grid_nw, 256, 0, stream>>>(rowp, esrc, Sv, Dv, XWh, b1, Hh, stp1);
    fold1<<<33, 256, 0, stream>>>(stp1, g1, be1, W2, WT2h, brow2);

    // ---- layer 2 ----
    gemm_sd<256, true><<<GEMM_BLOCKS, 256, 0, stream>>>(
        Hh, WT2h, brow2, as2, ad2, XWh, Sv, Dv);
    gat_aggregate<<<grid_nw, 256, 0, stream>>>(rowp, esrc, Sv, Dv, XWh, b2, Hh, stp2);
    fold_wc<<<1, 256, 0, stream>>>(stp2, g2, be2, Wc, bc, Wcp, bcp);

    // ---- classifier ----
    classifier<<<grid_nw, 256, 0, stream>>>(Hh, Wcp, bcp, out);
}

// Round 19
// 523.010 us; speedup vs baseline: 1.0304x; 1.0304x over previous
//
#include <hip/hip_runtime.h>

#define N_NODES 50000
#define E_EDGES 1600000
#define E2 (E_EDGES + N_NODES)   // 1,650,000 with self loops
#define HEADS 4
#define F 256
#define OUTC 10
#define BN_EPS 1e-5f
#define NEG_SLOPE 0.2f
#define NSLICE 64                // stats atomic-spreading slices
#define SB 1024                  // scan block size
#define NB ((N_NODES + SB - 1) / SB)   // 49 scan blocks

// XCD-ranged edge processing (scatter + count): 8 dst-ranges
#define NXCD 8
#define NR (N_NODES / NXCD)                  // 6250 nodes per range
#define EPB 2048                             // edges per block-chunk
#define NCHUNK ((E2 + EPB - 1) / EPB)        // 806 chunks

// mega_prep block ranges
#define CXB (N_NODES * 128 / 4 / 256)        // 6250 convert_x blocks
#define CWB 128                               // convert_w1T blocks
#define CDB (NXCD * NCHUNK)                   // 6448 ranged count_deg blocks

#define GEMM_BLOCKS ((N_NODES + 63) / 64)    // 782

static_assert(N_NODES % 4 == 0, "grid_nw exact");
static_assert(N_NODES % NXCD == 0, "ranges exact");

typedef __attribute__((ext_vector_type(8))) short short8;
typedef __attribute__((ext_vector_type(4))) float f32x4;
typedef _Float16 f16;
typedef __attribute__((ext_vector_type(2))) _Float16 f16x2;

__device__ __forceinline__ unsigned short f2h(float f) {
    f16 h = (f16)f;
    return __builtin_bit_cast(unsigned short, h);
}
__device__ __forceinline__ float h2f(unsigned short b) {
    return (float)__builtin_bit_cast(f16, b);
}
__device__ __forceinline__ f16x2 u2h2(unsigned int u) {
    return __builtin_bit_cast(f16x2, u);
}
__device__ __forceinline__ unsigned int h22u(f16x2 h) {
    return __builtin_bit_cast(unsigned int, h);
}

// ---- fused prep: convert_x | convert_w1T | ranged count_deg ----
__global__ __launch_bounds__(256) void mega_prep(
    const float* __restrict__ X, unsigned short* __restrict__ Xh,
    const float* __restrict__ W1, unsigned short* __restrict__ WT,
    const int* __restrict__ eidx, int* __restrict__ deg)
{
    const int b = blockIdx.x;
    const int t = threadIdx.x;
    if (b < CXB) {
        const int i = b * 256 + t;                 // float4 index, exact
        float4 v = reinterpret_cast<const float4*>(X)[i];
        ushort4 o = { f2h(v.x), f2h(v.y), f2h(v.z), f2h(v.w) };
        reinterpret_cast<ushort4*>(Xh)[i] = o;
    } else if (b < CXB + CWB) {
        const int k = b - CXB;                     // W1 row
        WT[t * 128 + k] = f2h(W1[k * 256 + t]);
    } else {
        const int b2 = b - CXB - CWB;
        const int r = b2 & (NXCD - 1);
        const int chunk = b2 >> 3;
        const int lo = r * NR;
        const int base = chunk * EPB;
        for (int i = t; i < EPB; i += 256) {
            const int e = base + i;
            if (e >= E2) break;
            int dst = (e < E_EDGES) ? eidx[E_EDGES + e] : e - E_EDGES;
            if ((unsigned)(dst - lo) >= (unsigned)NR) continue;
            atomicAdd(&deg[dst], 1);
        }
    }
}

// ---- parallel scan, 2 dispatches (R15-proven) ----
__global__ __launch_bounds__(SB) void scan_blocks(
    const int* __restrict__ deg, int* __restrict__ rowptr, int* __restrict__ bsum)
{
    __shared__ int sm[SB];
    const int t = threadIdx.x;
    const int idx = blockIdx.x * SB + t;
    int v = (idx < N_NODES) ? deg[idx] : 0;
    sm[t] = v;
    __syncthreads();
    for (int off = 1; off < SB; off <<= 1) {
        int u = (t >= off) ? sm[t - off] : 0;
        __syncthreads();
        sm[t] += u;
        __syncthreads();
    }
    if (idx < N_NODES) rowptr[idx] = sm[t] - v;   // exclusive within block
    if (t == SB - 1) bsum[blockIdx.x] = sm[t];
}

__global__ __launch_bounds__(SB) void scan_add2(
    int* __restrict__ rowptr, const int* __restrict__ bsum)
{
    __shared__ int boff_s;
    if (threadIdx.x == 0) {
        int run = 0;
        for (int b = 0; b < (int)blockIdx.x; b++) run += bsum[b];
        boff_s = run;
        if (blockIdx.x == 0) {
            int tot = 0;
            for (int b = 0; b < NB; b++) tot += bsum[b];
            rowptr[N_NODES] = tot;
        }
    }
    __syncthreads();
    const int idx = blockIdx.x * SB + threadIdx.x;
    if (idx < N_NODES) rowptr[idx] += boff_s;
}

// ------- FUSED: layer-1 MFMA GEMM (fp16) + ranged edge scatter ---------
// Best-measured configuration (R17, 528.7 us total). The scatter body
// pays some L2-eviction WRITE amplification, but overlap with the
// compute-dense gemm body nets out ahead of running them serially.
__global__ __launch_bounds__(256) void gemm1_scatter(
    const unsigned short* __restrict__ A, const unsigned short* __restrict__ BT,
    const float* __restrict__ a_src, const float* __restrict__ a_dst,
    unsigned short* __restrict__ C, float* __restrict__ S, float* __restrict__ D,
    const int* __restrict__ eidx, const int* __restrict__ rowptr,
    int* __restrict__ cursor, int* __restrict__ esrc)
{
    if (blockIdx.x >= GEMM_BLOCKS) {
        // ---- scatter body (ranged, R15 form) ----
        const int b2 = blockIdx.x - GEMM_BLOCKS;
        const int r = b2 & (NXCD - 1);
        const int chunk = b2 >> 3;
        const int lo = r * NR;
        const int base = chunk * EPB;
        for (int i = threadIdx.x; i < EPB; i += 256) {
            const int e = base + i;
            if (e >= E2) break;
            int dst = (e < E_EDGES) ? eidx[E_EDGES + e] : e - E_EDGES;
            if ((unsigned)(dst - lo) >= (unsigned)NR) continue;
            int src = (e < E_EDGES) ? eidx[e] : dst;
            int pos = atomicAdd(&cursor[dst], 1);
            esrc[rowptr[dst] + pos] = src;
        }
        return;
    }
    // ---- gemm body (K=128, no brow) ----
    const int t = threadIdx.x;
    const int wave = t >> 6, lane = t & 63;
    const int lo = lane & 15, hi = lane >> 4;
    const int row0 = blockIdx.x * 64;
    const int nbase = wave * 64;
    const int K = 128;

    int arow[4];
#pragma unroll
    for (int m = 0; m < 4; m++)
        arow[m] = min(row0 + m * 16 + lo, N_NODES - 1);

    f32x4 acc[4][4];
#pragma unroll
    for (int m = 0; m < 4; m++)
#pragma unroll
        for (int n = 0; n < 4; n++)
            acc[m][n] = (f32x4){0.f, 0.f, 0.f, 0.f};

    for (int k0 = 0; k0 < K; k0 += 32) {
        const int kk = k0 + hi * 8;
        short8 af[4], bfr[4];
#pragma unroll
        for (int m = 0; m < 4; m++)
            af[m] = *reinterpret_cast<const short8*>(A + (size_t)arow[m] * K + kk);
#pragma unroll
        for (int n = 0; n < 4; n++)
            bfr[n] = *reinterpret_cast<const short8*>(BT + (size_t)(nbase + n * 16 + lo) * K + kk);
#pragma unroll
        for (int m = 0; m < 4; m++)
#pragma unroll
            for (int n = 0; n < 4; n++)
                acc[m][n] = __builtin_amdgcn_mfma_f32_16x16x32_f16(
                    af[m], bfr[n], acc[m][n], 0, 0, 0);
    }

    float asv[4], adv[4];
#pragma unroll
    for (int n = 0; n < 4; n++) {
        int col = nbase + n * 16 + lo;
        asv[n] = a_src[col];
        adv[n] = a_dst[col];
    }

#pragma unroll
    for (int m = 0; m < 4; m++) {
#pragma unroll
        for (int i = 0; i < 4; i++) {
            const int row = row0 + m * 16 + hi * 4 + i;
            const bool ok = row < N_NODES;
            float ps = 0.f, pd = 0.f;
#pragma unroll
            for (int n = 0; n < 4; n++) {
                float v = acc[m][n][i];
                ps += v * asv[n];
                pd += v * adv[n];
                if (ok) C[(size_t)row * F + nbase + n * 16 + lo] = f2h(v);
            }
#pragma unroll
            for (int off = 1; off < 16; off <<= 1) {
                ps += __shfl_xor(ps, off, 64);
                pd += __shfl_xor(pd, off, 64);
            }
            if (lo == 0 && ok) {
                S[row * HEADS + wave] = ps;
                D[row * HEADS + wave] = pd;
            }
        }
    }
}

// ------- MFMA GEMM (fp16) + fused S/D (layer 2, with brow) -------------
template<int K, bool BROW>
__global__ __launch_bounds__(256) void gemm_sd(
    const unsigned short* __restrict__ A, const unsigned short* __restrict__ BT,
    const float* __restrict__ brow, const float* __restrict__ a_src,
    const float* __restrict__ a_dst, unsigned short* __restrict__ C,
    float* __restrict__ S, float* __restrict__ D)
{
    const int t = threadIdx.x;
    const int wave = t >> 6, lane = t & 63;
    const int lo = lane & 15, hi = lane >> 4;
    const int row0 = blockIdx.x * 64;
    const int nbase = wave * 64;

    int arow[4];
#pragma unroll
    for (int m = 0; m < 4; m++)
        arow[m] = min(row0 + m * 16 + lo, N_NODES - 1);

    f32x4 acc[4][4];
#pragma unroll
    for (int m = 0; m < 4; m++)
#pragma unroll
        for (int n = 0; n < 4; n++)
            acc[m][n] = (f32x4){0.f, 0.f, 0.f, 0.f};

    for (int k0 = 0; k0 < K; k0 += 32) {
        const int kk = k0 + hi * 8;
        short8 af[4], bfr[4];
#pragma unroll
        for (int m = 0; m < 4; m++)
            af[m] = *reinterpret_cast<const short8*>(A + (size_t)arow[m] * K + kk);
#pragma unroll
        for (int n = 0; n < 4; n++)
            bfr[n] = *reinterpret_cast<const short8*>(BT + (size_t)(nbase + n * 16 + lo) * K + kk);
#pragma unroll
        for (int m = 0; m < 4; m++)
#pragma unroll
            for (int n = 0; n < 4; n++)
                acc[m][n] = __builtin_amdgcn_mfma_f32_16x16x32_f16(
                    af[m], bfr[n], acc[m][n], 0, 0, 0);
    }

    float bb[4], asv[4], adv[4];
#pragma unroll
    for (int n = 0; n < 4; n++) {
        int col = nbase + n * 16 + lo;
        bb[n]  = BROW ? brow[col] : 0.f;
        asv[n] = a_src[col];
        adv[n] = a_dst[col];
    }

#pragma unroll
    for (int m = 0; m < 4; m++) {
#pragma unroll
        for (int i = 0; i < 4; i++) {
            const int row = row0 + m * 16 + hi * 4 + i;
            const bool ok = row < N_NODES;
            float ps = 0.f, pd = 0.f;
#pragma unroll
            for (int n = 0; n < 4; n++) {
                float v = acc[m][n][i] + bb[n];
                ps += v * asv[n];
                pd += v * adv[n];
                if (ok) C[(size_t)row * F + nbase + n * 16 + lo] = f2h(v);
            }
#pragma unroll
            for (int off = 1; off < 16; off <<= 1) {
                ps += __shfl_xor(ps, off, 64);
                pd += __shfl_xor(pd, off, 64);
            }
            if (lo == 0 && ok) {
                S[row * HEADS + wave] = ps;
                D[row * HEADS + wave] = pd;
            }
        }
    }
}

// ------- fused softmax + aggregation + bias + ReLU + sliced stats ------
// R16-proven fp16 inner loop (118-120 us, VGPR 32, occ ~80%).
__global__ __launch_bounds__(256) void gat_aggregate(
    const int* __restrict__ rowptr, const int* __restrict__ esrc,
    const float* __restrict__ S, const float* __restrict__ D,
    const unsigned short* __restrict__ XWh, const float* __restrict__ bias,
    unsigned short* __restrict__ Hh, float* __restrict__ stp)
{
    __shared__ int          sbuf[4][64];
    __shared__ unsigned int wbuf[4][64][4];   // half2-packed w per head
    __shared__ float red_s[4][F];
    __shared__ float red_q[4][F];
    const int wv   = threadIdx.x >> 6;
    const int lane = threadIdx.x & 63;
    const int dst  = blockIdx.x * 4 + wv;
    const int beg = rowptr[dst], end = rowptr[dst + 1];
    const int h = lane >> 4;
    const float4 d4 = *reinterpret_cast<const float4*>(D + dst * HEADS);

    f16x2 a01a = {0, 0}, a23a = {0, 0}, dna = {0, 0};
    f16x2 a01b = {0, 0}, a23b = {0, 0}, dnb = {0, 0};

    for (int i = beg; i < end; i += 64) {
        const int nb = min(64, end - i);
        const bool valid = (i + lane < end);
        const int mysrc = valid ? esrc[i + lane] : 0;
        float4 w4 = {0.f, 0.f, 0.f, 0.f};
        if (valid) {
            const float4 s4 = *reinterpret_cast<const float4*>(S + mysrc * HEADS);
            float z;
            z = s4.x + d4.x; w4.x = __expf(z > 0.f ? z : NEG_SLOPE * z);
            z = s4.y + d4.y; w4.y = __expf(z > 0.f ? z : NEG_SLOPE * z);
            z = s4.z + d4.z; w4.z = __expf(z > 0.f ? z : NEG_SLOPE * z);
            z = s4.w + d4.w; w4.w = __expf(z > 0.f ? z : NEG_SLOPE * z);
        }
        sbuf[wv][lane] = mysrc;
        {
            f16 hx = (f16)w4.x, hy = (f16)w4.y, hz = (f16)w4.z, hw = (f16)w4.w;
            wbuf[wv][lane][0] = h22u((f16x2){hx, hx});
            wbuf[wv][lane][1] = h22u((f16x2){hy, hy});
            wbuf[wv][lane][2] = h22u((f16x2){hz, hz});
            wbuf[wv][lane][3] = h22u((f16x2){hw, hw});
        }

        int j = 0;
        for (; j + 7 < nb; j += 8) {
            int s0 = sbuf[wv][j + 0], s1 = sbuf[wv][j + 1];
            int s2 = sbuf[wv][j + 2], s3 = sbuf[wv][j + 3];
            int s4i = sbuf[wv][j + 4], s5 = sbuf[wv][j + 5];
            int s6 = sbuf[wv][j + 6], s7 = sbuf[wv][j + 7];
            f16x2 w0 = u2h2(wbuf[wv][j + 0][h]), w1 = u2h2(wbuf[wv][j + 1][h]);
            f16x2 w2 = u2h2(wbuf[wv][j + 2][h]), w3 = u2h2(wbuf[wv][j + 3][h]);
            f16x2 w4f = u2h2(wbuf[wv][j + 4][h]), w5 = u2h2(wbuf[wv][j + 5][h]);
            f16x2 w6 = u2h2(wbuf[wv][j + 6][h]), w7 = u2h2(wbuf[wv][j + 7][h]);
            uint2 x0 = *reinterpret_cast<const uint2*>(XWh + (size_t)s0 * F + lane * 4);
            uint2 x1 = *reinterpret_cast<const uint2*>(XWh + (size_t)s1 * F + lane * 4);
            uint2 x2 = *reinterpret_cast<const uint2*>(XWh + (size_t)s2 * F + lane * 4);
            uint2 x3 = *reinterpret_cast<const uint2*>(XWh + (size_t)s3 * F + lane * 4);
            uint2 x4 = *reinterpret_cast<const uint2*>(XWh + (size_t)s4i * F + lane * 4);
            uint2 x5 = *reinterpret_cast<const uint2*>(XWh + (size_t)s5 * F + lane * 4);
            uint2 x6 = *reinterpret_cast<const uint2*>(XWh + (size_t)s6 * F + lane * 4);
            uint2 x7 = *reinterpret_cast<const uint2*>(XWh + (size_t)s7 * F + lane * 4);
            a01a += w0 * u2h2(x0.x); a23a += w0 * u2h2(x0.y); dna += w0;
            a01b += w1 * u2h2(x1.x); a23b += w1 * u2h2(x1.y); dnb += w1;
            a01a += w2 * u2h2(x2.x); a23a += w2 * u2h2(x2.y); dna += w2;
            a01b += w3 * u2h2(x3.x); a23b += w3 * u2h2(x3.y); dnb += w3;
            a01a += w4f * u2h2(x4.x); a23a += w4f * u2h2(x4.y); dna += w4f;
            a01b += w5 * u2h2(x5.x); a23b += w5 * u2h2(x5.y); dnb += w5;
            a01a += w6 * u2h2(x6.x); a23a += w6 * u2h2(x6.y); dna += w6;
            a01b += w7 * u2h2(x7.x); a23b += w7 * u2h2(x7.y); dnb += w7;
        }
        for (; j < nb; j++) {
            int src = sbuf[wv][j];
            f16x2 wj = u2h2(wbuf[wv][j][h]);
            uint2 xv = *reinterpret_cast<const uint2*>(XWh + (size_t)src * F + lane * 4);
            a01a += wj * u2h2(xv.x); a23a += wj * u2h2(xv.y); dna += wj;
        }
    }

    const float ax = (float)a01a.x + (float)a01b.x;
    const float ay = (float)a01a.y + (float)a01b.y;
    const float az = (float)a23a.x + (float)a23b.x;
    const float aw = (float)a23a.y + (float)a23b.y;
    const float den = (float)dna.x + (float)dnb.x;
    const float inv = 1.f / (den + 1e-16f);
    float4 bv = *reinterpret_cast<const float4*>(bias + lane * 4);
    float v0 = ax * inv + bv.x, v1 = ay * inv + bv.y;
    float v2 = az * inv + bv.z, v3 = aw * inv + bv.w;
    v0 = v0 > 0.f ? v0 : 0.f; v1 = v1 > 0.f ? v1 : 0.f;
    v2 = v2 > 0.f ? v2 : 0.f; v3 = v3 > 0.f ? v3 : 0.f;
    ushort4 o = { f2h(v0), f2h(v1), f2h(v2), f2h(v3) };
    *reinterpret_cast<ushort4*>(Hh + (size_t)dst * F + lane * 4) = o;

    f32x4 rs = {v0, v1, v2, v3};
    f32x4 rq = {v0 * v0, v1 * v1, v2 * v2, v3 * v3};
    *reinterpret_cast<f32x4*>(&red_s[wv][lane * 4]) = rs;
    *reinterpret_cast<f32x4*>(&red_q[wv][lane * 4]) = rq;
    __syncthreads();
    const int ch = threadIdx.x;
    float s = (red_s[0][ch] + red_s[1][ch]) + (red_s[2][ch] + red_s[3][ch]);
    float q = (red_q[0][ch] + red_q[1][ch]) + (red_q[2][ch] + red_q[3][ch]);
    float* slice = stp + (size_t)(blockIdx.x & (NSLICE - 1)) * (2 * F);
    atomicAdd(&slice[ch], s);
    atomicAdd(&slice[F + ch], q);
}

// ---- fold BN1 into W2 + brow, ONE kernel, 33 blocks (R14-proven) ----
__global__ __launch_bounds__(256) void fold1(
    const float* __restrict__ stp, const float* __restrict__ g,
    const float* __restrict__ be, const float* __restrict__ W2,
    unsigned short* __restrict__ WT2h, float* __restrict__ brow)
{
    __shared__ float sc_l[F], sh_l[F];
    const int t = threadIdx.x;
    float s = 0.f, q = 0.f;
    for (int b = 0; b < NSLICE; b++) {       // fixed order
        s += stp[(size_t)b * 2 * F + t];
        q += stp[(size_t)b * 2 * F + F + t];
    }
    const float inv_n = 1.f / (float)N_NODES;
    float mu = s * inv_n;
    float var = q * inv_n - mu * mu;
    float sc = rsqrtf(var + BN_EPS) * g[t];
    sc_l[t] = sc;
    sh_l[t] = be[t] - mu * sc;
    __syncthreads();
    if (blockIdx.x < 32) {
        const int k0 = blockIdx.x * 8;
#pragma unroll
        for (int kk = 0; kk < 8; kk++)
            WT2h[(size_t)t * F + k0 + kk] = f2h(W2[(size_t)(k0 + kk) * F + t] * sc_l[k0 + kk]);
    } else {
        float acc = 0.f;
        for (int k = 0; k < F; k++)
            acc += sh_l[k] * W2[(size_t)k * F + t];
        brow[t] = acc;
    }
}

// ---- BN2 prep + fold into classifier weights, 1 block (R14-proven) ----
__global__ __launch_bounds__(256) void fold_wc(
    const float* __restrict__ stp, const float* __restrict__ g,
    const float* __restrict__ be, const float* __restrict__ Wc,
    const float* __restrict__ bc, float* __restrict__ Wcp, float* __restrict__ bcp)
{
    __shared__ float sc_l[F], sh_l[F];
    __shared__ float red[256][OUTC];
    const int t = threadIdx.x;
    float s = 0.f, q = 0.f;
    for (int b = 0; b < NSLICE; b++) {       // fixed order
        s += stp[(size_t)b * 2 * F + t];
        q += stp[(size_t)b * 2 * F + F + t];
    }
    const float inv_n = 1.f / (float)N_NODES;
    float mu = s * inv_n;
    float var = q * inv_n - mu * mu;
    float sc = rsqrtf(var + BN_EPS) * g[t];
    sc_l[t] = sc;
    sh_l[t] = be[t] - mu * sc;
    const float sh_t = be[t] - mu * sc;
#pragma unroll
    for (int o = 0; o < OUTC; o++) {
        float wv = Wc[t * OUTC + o];
        Wcp[t * OUTC + o] = wv * sc;
        red[t][o] = sh_t * wv;
    }
    __syncthreads();
    for (int off = 128; off > 0; off >>= 1) {
        if (t < off) {
#pragma unroll
            for (int o = 0; o < OUTC; o++)
                red[t][o] += red[t + off][o];
        }
        __syncthreads();
    }
    if (t < OUTC) bcp[t] = bc[t] + red[0][t];
}

// ---------------- classifier: [N,256]fp16 @ Wcp[256,10] + bcp --------
__global__ __launch_bounds__(256) void classifier(
    const unsigned short* __restrict__ Hh, const float* __restrict__ Wcp,
    const float* __restrict__ bcp, float* __restrict__ out)
{
    __shared__ float wls[F][OUTC + 1];
    const int t = threadIdx.x;
    for (int i = t; i < F * OUTC; i += 256)
        wls[i / OUTC][i % OUTC] = Wcp[i];
    __syncthreads();

    const int wave = t >> 6, lane = t & 63;
    const int n = blockIdx.x * 4 + wave;
    if (n >= N_NODES) return;

    float v[4];
#pragma unroll
    for (int j = 0; j < 4; j++)
        v[j] = h2f(Hh[(size_t)n * F + j * 64 + lane]);

    float acc[OUTC];
#pragma unroll
    for (int o = 0; o < OUTC; o++) acc[o] = 0.f;
#pragma unroll
    for (int j = 0; j < 4; j++)
#pragma unroll
        for (int o = 0; o < OUTC; o++)
            acc[o] += v[j] * wls[j * 64 + lane][o];

#pragma unroll
    for (int off = 32; off > 0; off >>= 1)
#pragma unroll
        for (int o = 0; o < OUTC; o++)
            acc[o] += __shfl_xor(acc[o], off, 64);

    if (lane == 0) {
#pragma unroll
        for (int o = 0; o < OUTC; o++)
            out[(size_t)n * OUTC + o] = acc[o] + bcp[o];
    }
}

extern "C" void kernel_launch(void* const* d_in, const int* in_sizes, int n_in,
                              void* d_out, int out_size, void* d_ws, size_t ws_size,
                              hipStream_t stream)
{
    const float* x   = (const float*)d_in[0];
    const int*   ei  = (const int*)d_in[1];
    const float* W1  = (const float*)d_in[2];
    const float* as1 = (const float*)d_in[3];
    const float* ad1 = (const float*)d_in[4];
    const float* b1  = (const float*)d_in[5];
    const float* W2  = (const float*)d_in[6];
    const float* as2 = (const float*)d_in[7];
    const float* ad2 = (const float*)d_in[8];
    const float* b2  = (const float*)d_in[9];
    const float* g1  = (const float*)d_in[10];
    const float* be1 = (const float*)d_in[11];
    const float* g2  = (const float*)d_in[12];
    const float* be2 = (const float*)d_in[13];
    const float* Wc  = (const float*)d_in[14];
    const float* bc  = (const float*)d_in[15];
    float* out = (float*)d_out;

    char* w = (char*)d_ws;
    // zero-init region first (one memset): deg | cursor | stp1 | stp2
    int*   deg   = (int*)w;                      w += (size_t)N_NODES * 4;
    int*   cursor= (int*)w;                      w += (size_t)N_NODES * 4;
    float* stp1  = (float*)w;                    w += (size_t)NSLICE * 2 * F * 4;
    float* stp2  = (float*)w;                    w += (size_t)NSLICE * 2 * F * 4;
    const size_t zero_bytes = (size_t)N_NODES * 8 + (size_t)NSLICE * 2 * F * 8;

    unsigned short* Xh   = (unsigned short*)w;   w += (size_t)N_NODES * 128 * 2;
    unsigned short* XWh  = (unsigned short*)w;   w += (size_t)N_NODES * F * 2;
    unsigned short* Hh   = (unsigned short*)w;   w += (size_t)N_NODES * F * 2;
    unsigned short* WT1h = (unsigned short*)w;   w += 256 * 128 * 2;
    unsigned short* WT2h = (unsigned short*)w;   w += 256 * 256 * 2;
    float* Wcp   = (float*)w;                    w += F * OUTC * 4;
    float* bcp   = (float*)w;                    w += 64;
    float* brow2 = (float*)w;                    w += F * 4;
    float* Sv    = (float*)w;                    w += (size_t)N_NODES * HEADS * 4;
    float* Dv    = (float*)w;                    w += (size_t)N_NODES * HEADS * 4;
    int* rowp    = (int*)w;                      w += (size_t)(N_NODES + 1) * 4;
    int* bsum    = (int*)w;                      w += NB * 4;
    int* esrc    = (int*)w;                      /* E2 ints */

    const int grid_nw   = N_NODES / 4;           // 12500
    const int grid_prep = CXB + CWB + CDB;       // 12826
    const int grid_g1s  = GEMM_BLOCKS + NXCD * NCHUNK;  // 782 + 6448

    // ---- prep ----
    hipMemsetAsync(deg, 0, zero_bytes, stream);
    mega_prep<<<grid_prep, 256, 0, stream>>>(x, Xh, W1, WT1h, ei, deg);
    scan_blocks<<<NB, SB, 0, stream>>>(deg, rowp, bsum);
    scan_add2<<<NB, SB, 0, stream>>>(rowp, bsum);

    // ---- layer 1 GEMM overlapped with CSR scatter ----
    gemm1_scatter<<<grid_g1s, 256, 0, stream>>>(
        Xh, WT1h, as1, ad1, XWh, Sv, Dv, ei, rowp, cursor, esrc);
    gat_aggregate<<<grid_nw, 256, 0, stream>>>(rowp, esrc, Sv, Dv, XWh, b1, Hh, stp1);
    fold1<<<33, 256, 0, stream>>>(stp1, g1, be1, W2, WT2h, brow2);

    // ---- layer 2 ----
    gemm_sd<256, true><<<GEMM_BLOCKS, 256, 0, stream>>>(
        Hh, WT2h, brow2, as2, ad2, XWh, Sv, Dv);
    gat_aggregate<<<grid_nw, 256, 0, stream>>>(rowp, esrc, Sv, Dv, XWh, b2, Hh, stp2);
    fold_wc<<<1, 256, 0, stream>>>(stp2, g2, be2, Wc, bc, Wcp, bcp);

    // ---- classifier ----
    classifier<<<grid_nw, 256, 0, stream>>>(Hh, Wcp, bcp, out);
}